// Round 3
// baseline (1946.333 us; speedup 1.0000x reference)
//
#include <hip/hip_runtime.h>
#include <hip/hip_bf16.h>

// IntraPatchGraphAggregator: N=8192 patches, L=64, D=256, H=4, DH=64, TAU=300
// One workgroup (4 waves) per patch. bf16 MFMA 16x16x32, f32 accum.
// R3: no X LDS tile (global f32 frags) -> 37.8KB LDS -> 3 blocks/CU;
//     transposed products so all tile writebacks are packed ushort4 (b64).

typedef __attribute__((ext_vector_type(8))) short short8;   // 8 bf16
typedef __attribute__((ext_vector_type(4))) float f32x4;

__device__ __forceinline__ unsigned short f2b(float x) {   // f32 -> bf16 RNE
  unsigned int u = __float_as_uint(x);
  u += 0x7FFFu + ((u >> 16) & 1u);
  return (unsigned short)(u >> 16);
}
__device__ __forceinline__ float b2f(unsigned short b) {
  return __uint_as_float(((unsigned int)b) << 16);
}
__device__ __forceinline__ short8 pack8(float4 a, float4 b) {
  short8 r;
  r[0] = (short)f2b(a.x); r[1] = (short)f2b(a.y);
  r[2] = (short)f2b(a.z); r[3] = (short)f2b(a.w);
  r[4] = (short)f2b(b.x); r[5] = (short)f2b(b.y);
  r[6] = (short)f2b(b.z); r[7] = (short)f2b(b.w);
  return r;
}

// ---- weight conversion: Wq|Wk|Wv -> Wqkv_b [768][256], Wo -> Wo_b [256][256]
__global__ void wconv_kernel(const float* __restrict__ Wq, const float* __restrict__ Wk,
                             const float* __restrict__ Wv, const float* __restrict__ Wo,
                             unsigned short* __restrict__ dst) {
  int e = blockIdx.x * 256 + threadIdx.x;   // 0 .. 262143
  int row = e >> 8, col = e & 255;
  float v;
  if (row < 256)      v = Wq[(row << 8) | col];
  else if (row < 512) v = Wk[((row - 256) << 8) | col];
  else if (row < 768) v = Wv[((row - 512) << 8) | col];
  else                v = Wo[((row - 768) << 8) | col];
  dst[e] = f2b(v);
}

__global__ __launch_bounds__(256, 3) void patch_attn_kernel(
    const float* __restrict__ tokens, const float* __restrict__ ts,
    const float* __restrict__ maskp,
    const unsigned short* __restrict__ Wqkv,  // [768][256]: Wq | Wk | Wv rows
    const unsigned short* __restrict__ Wob,   // [256][256]
    const float* __restrict__ bq, const float* __restrict__ bk,
    const float* __restrict__ bv, const float* __restrict__ bo,
    const float* __restrict__ readout, float* __restrict__ outp) {
  // T[0]=Q (later O), T[1]=K, T[2]=V^T, T[3]=P; epilogue: T[w] = outT (d_local x token)
  // row stride 72 ushort = 144B = 36 dwords -> bank stride 4: b128 frag reads are
  // throughput-optimal (8 lanes per 4-bank group); all stores are b64 (ushort4).
  __shared__ unsigned short T[4][64][72];
  __shared__ float tl[64], ml[64], mneg[64];
  __shared__ float ps[4][64];

  const int n   = blockIdx.x;
  const int tid = threadIdx.x;
  const int w   = tid >> 6;    // wave 0..3
  const int l   = tid & 63;
  const int l16 = l & 15;
  const int lq  = l >> 4;      // 0..3

  if (tid < 64) {
    tl[tid] = ts[n * 64 + tid];
    float mk = maskp[n * 64 + tid];
    ml[tid]   = mk;
    mneg[tid] = (mk > 0.0f) ? 0.0f : -1e9f;
  }
  __syncthreads();

  const float4* Xg4 = (const float4*)(tokens + (size_t)n * (64 * 256));
  const float tq = tl[16 * w + l16];          // this lane's query timestamp (all heads)

  const f32x4 fz = {0.f, 0.f, 0.f, 0.f};
  f32x4 oacc[4][4];                           // out rows 16rf+4lq+i, cols 64w+16j+l16
  #pragma unroll
  for (int a = 0; a < 4; ++a)
    #pragma unroll
    for (int b = 0; b < 4; ++b) oacc[a][b] = fz;

  #pragma unroll 1
  for (int h = 0; h < 4; ++h) {
    // ========== QKV: Q^T = Wq_h X^T, K^T = Wk_h X^T (A=W, B=X); V = X Wv_h^T ==========
    // wave w: dh-slice 16w..16w+15 (Q,K rows / V cols); tokens all (j / rf).
    f32x4 qac[4], kac[4], vac[4];
    #pragma unroll
    for (int j = 0; j < 4; ++j) { qac[j] = fz; kac[j] = fz; vac[j] = fz; }

    const unsigned short* wqp = Wqkv + (size_t)((0 * 256 + h * 64 + 16 * w + l16) * 256 + lq * 8);
    const unsigned short* wkp = Wqkv + (size_t)((1 * 256 + h * 64 + 16 * w + l16) * 256 + lq * 8);
    const unsigned short* wvp = Wqkv + (size_t)((2 * 256 + h * 64 + 16 * w + l16) * 256 + lq * 8);

    #pragma unroll
    for (int ks = 0; ks < 8; ++ks) {
      short8 xf[4];                          // X rows 16rf+l16, k-slice (A or B frag)
      #pragma unroll
      for (int rf = 0; rf < 4; ++rf) {
        const float4* p = Xg4 + (16 * rf + l16) * 64 + ks * 8 + lq * 2;
        xf[rf] = pack8(p[0], p[1]);
      }
      short8 wq = *(const short8*)(wqp + ks * 32);
      short8 wk = *(const short8*)(wkp + ks * 32);
      short8 wv = *(const short8*)(wvp + ks * 32);
      #pragma unroll
      for (int j = 0; j < 4; ++j)
        qac[j] = __builtin_amdgcn_mfma_f32_16x16x32_bf16(wq, xf[j], qac[j], 0, 0, 0);
      #pragma unroll
      for (int j = 0; j < 4; ++j)
        kac[j] = __builtin_amdgcn_mfma_f32_16x16x32_bf16(wk, xf[j], kac[j], 0, 0, 0);
      #pragma unroll
      for (int rf = 0; rf < 4; ++rf)
        vac[rf] = __builtin_amdgcn_mfma_f32_16x16x32_bf16(xf[rf], wv, vac[rf], 0, 0, 0);
    }
    // packed writebacks (all ushort4/b64)
    {
      float4 bq4 = *(const float4*)&bq[h * 64 + 16 * w + 4 * lq];
      float4 bk4 = *(const float4*)&bk[h * 64 + 16 * w + 4 * lq];
      float  bvv = bv[h * 64 + 16 * w + l16];
      #pragma unroll
      for (int j = 0; j < 4; ++j) {
        // D_j (Q^T): col=token 16j+l16, row=dh 16w+4lq+i  -> Qh[token][dh] packed over i
        ushort4 q4, k4;
        q4.x = f2b(qac[j][0] + bq4.x); q4.y = f2b(qac[j][1] + bq4.y);
        q4.z = f2b(qac[j][2] + bq4.z); q4.w = f2b(qac[j][3] + bq4.w);
        *(ushort4*)&T[0][16 * j + l16][16 * w + 4 * lq] = q4;
        k4.x = f2b(kac[j][0] + bk4.x); k4.y = f2b(kac[j][1] + bk4.y);
        k4.z = f2b(kac[j][2] + bk4.z); k4.w = f2b(kac[j][3] + bk4.w);
        *(ushort4*)&T[1][16 * j + l16][16 * w + 4 * lq] = k4;
      }
      #pragma unroll
      for (int rf = 0; rf < 4; ++rf) {
        // D_rf (V): col=dh 16w+l16, row=token 16rf+4lq+i -> VhT[dh][token] packed over i
        ushort4 v4;
        v4.x = f2b(vac[rf][0] + bvv); v4.y = f2b(vac[rf][1] + bvv);
        v4.z = f2b(vac[rf][2] + bvv); v4.w = f2b(vac[rf][3] + bvv);
        *(ushort4*)&T[2][16 * w + l16][16 * rf + 4 * lq] = v4;
      }
    }
    __syncthreads();

    // ========== S^T = K Q^T: wave w -> q-cols 16w..16w+15, kk all (j) ==========
    f32x4 sac[4];
    #pragma unroll
    for (int j = 0; j < 4; ++j) sac[j] = fz;
    #pragma unroll
    for (int ks = 0; ks < 2; ++ks) {
      short8 qf = *(const short8*)&T[0][16 * w + l16][ks * 32 + lq * 8];  // B: col=q
      #pragma unroll
      for (int j = 0; j < 4; ++j) {
        short8 kf = *(const short8*)&T[1][16 * j + l16][ks * 32 + lq * 8]; // A: row=kk
        sac[j] = __builtin_amdgcn_mfma_f32_16x16x32_bf16(kf, qf, sac[j], 0, 0, 0);
      }
    }
    // lane holds S[q=16w+l16][kk=16j+4lq+i] -> softmax reduce over lq group (2 shfl)
    {
      float sv[4][4], mx = -3e38f;
      #pragma unroll
      for (int j = 0; j < 4; ++j) {
        float4 t4 = *(const float4*)&tl[16 * j + 4 * lq];
        float4 m4 = *(const float4*)&mneg[16 * j + 4 * lq];
        float s0 = sac[j][0] * 0.125f - fabsf(tq - t4.x) * (1.0f / 300.0f) + m4.x;
        float s1 = sac[j][1] * 0.125f - fabsf(tq - t4.y) * (1.0f / 300.0f) + m4.y;
        float s2 = sac[j][2] * 0.125f - fabsf(tq - t4.z) * (1.0f / 300.0f) + m4.z;
        float s3 = sac[j][3] * 0.125f - fabsf(tq - t4.w) * (1.0f / 300.0f) + m4.w;
        sv[j][0] = s0; sv[j][1] = s1; sv[j][2] = s2; sv[j][3] = s3;
        mx = fmaxf(mx, fmaxf(fmaxf(s0, s1), fmaxf(s2, s3)));
      }
      mx = fmaxf(mx, __shfl_xor(mx, 16));
      mx = fmaxf(mx, __shfl_xor(mx, 32));
      float pv[4][4], sum = 0.f;
      #pragma unroll
      for (int j = 0; j < 4; ++j)
        #pragma unroll
        for (int i = 0; i < 4; ++i) { float e = __expf(sv[j][i] - mx); pv[j][i] = e; sum += e; }
      sum += __shfl_xor(sum, 16);
      sum += __shfl_xor(sum, 32);
      float inv = 1.0f / sum;
      #pragma unroll
      for (int j = 0; j < 4; ++j) {
        ushort4 a4;
        a4.x = f2b(pv[j][0] * inv); a4.y = f2b(pv[j][1] * inv);
        a4.z = f2b(pv[j][2] * inv); a4.w = f2b(pv[j][3] * inv);
        *(ushort4*)&T[3][16 * w + l16][16 * j + 4 * lq] = a4;   // P[q][kk] packed over i
      }
    }
    __syncthreads();

    // ========== O^T = V^T P^T: wave w -> d-rows 16w..16w+15, q all (j) ==========
    f32x4 oc[4];
    #pragma unroll
    for (int j = 0; j < 4; ++j) oc[j] = fz;
    #pragma unroll
    for (int ks = 0; ks < 2; ++ks) {
      short8 vf = *(const short8*)&T[2][16 * w + l16][ks * 32 + lq * 8];   // A: row=d
      #pragma unroll
      for (int j = 0; j < 4; ++j) {
        short8 af = *(const short8*)&T[3][16 * j + l16][ks * 32 + lq * 8]; // B: col=q
        oc[j] = __builtin_amdgcn_mfma_f32_16x16x32_bf16(vf, af, oc[j], 0, 0, 0);
      }
    }
    __syncthreads();   // all P/V reads done before overwriting T[0] (O into Q's tile)
    #pragma unroll
    for (int j = 0; j < 4; ++j) {
      // D_j: col=q 16j+l16, row=d 16w+4lq+i -> O[q][d] packed over i
      ushort4 o4;
      o4.x = f2b(oc[j][0]); o4.y = f2b(oc[j][1]);
      o4.z = f2b(oc[j][2]); o4.w = f2b(oc[j][3]);
      *(ushort4*)&T[0][16 * j + l16][16 * w + 4 * lq] = o4;
    }
    __syncthreads();

    // ========== out += O_h @ Wo_h^T: wave w -> out cols 64w..64w+63 ==========
    {
      const unsigned short* wop[4];
      #pragma unroll
      for (int j = 0; j < 4; ++j)
        wop[j] = Wob + (size_t)((64 * w + 16 * j + l16) * 256 + h * 64 + lq * 8);
      #pragma unroll
      for (int ks = 0; ks < 2; ++ks) {
        short8 ao[4];
        #pragma unroll
        for (int rf = 0; rf < 4; ++rf)
          ao[rf] = *(const short8*)&T[0][16 * rf + l16][ks * 32 + lq * 8];
        short8 bw[4];
        #pragma unroll
        for (int j = 0; j < 4; ++j) bw[j] = *(const short8*)(wop[j] + ks * 32);
        #pragma unroll
        for (int rf = 0; rf < 4; ++rf)
          #pragma unroll
          for (int j = 0; j < 4; ++j)
            oacc[rf][j] = __builtin_amdgcn_mfma_f32_16x16x32_bf16(ao[rf], bw[j], oacc[rf][j], 0, 0, 0);
      }
    }
    __syncthreads();   // tiles free for next head
  }

  // ---- epilogue: outT = ((O@Wo^T + bo) * mask)^T into wave-private tile T[w]
  #pragma unroll
  for (int j = 0; j < 4; ++j) {
    float bov = bo[64 * w + 16 * j + l16];
    #pragma unroll
    for (int rf = 0; rf < 4; ++rf) {
      float4 m4 = *(const float4*)&ml[16 * rf + 4 * lq];
      ushort4 t4;
      t4.x = f2b((oacc[rf][j][0] + bov) * m4.x);
      t4.y = f2b((oacc[rf][j][1] + bov) * m4.y);
      t4.z = f2b((oacc[rf][j][2] + bov) * m4.z);
      t4.w = f2b((oacc[rf][j][3] + bov) * m4.w);
      // outT[d_local=16j+l16][token=16rf+4lq+i]
      *(ushort4*)&T[w][16 * j + l16][16 * rf + 4 * lq] = t4;
    }
  }
  __syncthreads();

  // ---- learned-query pooling: wave w == head w; lane l == token (phase 1)
  {
    float acc = 0.f;
    #pragma unroll
    for (int d = 0; d < 64; ++d)
      acc += b2f(T[w][d][l]) * readout[64 * w + d];
    float logit = acc * 0.125f + mneg[l];
    float mx = logit;
    #pragma unroll
    for (int x = 1; x < 64; x <<= 1) mx = fmaxf(mx, __shfl_xor(mx, x));
    float p = __expf(logit - mx);
    float sm = p;
    #pragma unroll
    for (int x = 1; x < 64; x <<= 1) sm += __shfl_xor(sm, x);
    ps[w][l] = p / sm;
  }
  __syncthreads();
  {
    // lane l == output dim within head w: pooled[64w+l] = sum_k ps[k] * out[k][64w+l]
    float o = 0.f;
    #pragma unroll
    for (int kc = 0; kc < 16; ++kc) {
      ushort4 t4 = *(const ushort4*)&T[w][l][kc * 4];
      o += ps[w][kc * 4 + 0] * b2f(t4.x) + ps[w][kc * 4 + 1] * b2f(t4.y)
         + ps[w][kc * 4 + 2] * b2f(t4.z) + ps[w][kc * 4 + 3] * b2f(t4.w);
    }
    outp[(size_t)n * 256 + 64 * w + l] = o;
  }
}

extern "C" void kernel_launch(void* const* d_in, const int* in_sizes, int n_in,
                              void* d_out, int out_size, void* d_ws, size_t ws_size,
                              hipStream_t stream) {
  const float* tokens  = (const float*)d_in[0];
  const float* ts      = (const float*)d_in[1];
  const float* mask    = (const float*)d_in[2];
  const float* Wq      = (const float*)d_in[3];
  const float* bq      = (const float*)d_in[4];
  const float* Wk      = (const float*)d_in[5];
  const float* bk      = (const float*)d_in[6];
  const float* Wv      = (const float*)d_in[7];
  const float* bv      = (const float*)d_in[8];
  const float* Wo      = (const float*)d_in[9];
  const float* bo      = (const float*)d_in[10];
  const float* readout = (const float*)d_in[11];
  (void)n_in; (void)out_size; (void)ws_size;

  unsigned short* Wqkv_b = (unsigned short*)d_ws;        // 768*256 bf16
  unsigned short* Wo_b   = Wqkv_b + 768 * 256;           // 256*256 bf16 (total 512 KB)

  const int n_patches = in_sizes[0] / (64 * 256);

  wconv_kernel<<<1024, 256, 0, stream>>>(Wq, Wk, Wv, Wo, Wqkv_b);
  patch_attn_kernel<<<n_patches, 256, 0, stream>>>(
      tokens, ts, mask, Wqkv_b, Wo_b, bq, bk, bv, bo, readout, (float*)d_out);
}